// Round 3
// baseline (132.664 us; speedup 1.0000x reference)
//
#include <hip/hip_runtime.h>
#include <hip/hip_bf16.h>

// Problem: B=32, S=512, P=512, D=768
//   M = B*S = 16384 tokens, N = P = 512 prototypes, K = D = 768
// out[0 .. M*N)            = distances  ||x_m - p_n||^2  (fp32)
// out[M*N .. M*N + N*K)    = prototypes (fp32 passthrough)
//
// Single fused kernel: grid (N/128, M/128) = (4,128), 256 threads.
// Each block:
//   - streams its 128-row A-stripe (fp32) and 128-row B-tile (fp32) per
//     BK=64 chunk, converts to bf16 in-register, stages via ds_write
//     (A 4x-re-read across bn is LLC-absorbed: A=52MB << 256MB L3; B L2-hot)
//   - accumulates ||x||^2 / ||p||^2 in fp32 alongside the conversion
//     (exact norms; only the cross term is bf16-quantized)
//   - 4 waves 2x2, each 64x64 via 4x4 mfma_f32_16x16x32_bf16
//   - blockIdx.y==0 blocks write the fp32 prototype passthrough
//   - epilogue: out = xsq + psq - 2*acc

#define M_TOK 16384
#define N_PROT 512
#define K_DIM 768
#define BK 64

typedef __attribute__((ext_vector_type(4))) float f32x4;
typedef __attribute__((ext_vector_type(8))) short bf16x8;

__device__ inline unsigned short f2bf(float f) {
    // round-to-nearest-even on the bit pattern (finite inputs)
    unsigned int u = __float_as_uint(f);
    u += 0x7fffu + ((u >> 16) & 1u);
    return (unsigned short)(u >> 16);
}

__global__ __launch_bounds__(256, 2) void fused_dist_kernel(
    const float* __restrict__ X,    // [M,K] fp32 tokens
    const float* __restrict__ Pr,   // [N,K] fp32 prototypes
    float* __restrict__ out,        // [M,N] distances
    float* __restrict__ proto_out)  // [N,K] passthrough
{
    __shared__ unsigned short lds_a[128 * BK];   // 16 KB
    __shared__ unsigned short lds_b[128 * BK];   // 16 KB
    __shared__ float lds_xsq[128];
    __shared__ float lds_psq[128];

    const int tid  = threadIdx.x;
    const int wave = tid >> 6;
    const int lane = tid & 63;
    const int bm = blockIdx.y << 7;
    const int bn = blockIdx.x << 7;
    const int wm = (wave >> 1) << 6;   // wave row offset in block tile
    const int wn = (wave & 1) << 6;    // wave col offset
    const int quad = lane >> 4;        // 0..3
    const int l16  = lane & 15;

    // staging mapping: thread (r0, c4) loads float4 at rows r0+16p, cols c4*4
    const int r0 = tid >> 4;           // 0..15
    const int c4 = tid & 15;           // 0..15 (float4 column in 64-col chunk)
    const bool write_proto = (blockIdx.y == 0);

    float asq[8], bsq[8];
#pragma unroll
    for (int p = 0; p < 8; ++p) { asq[p] = 0.0f; bsq[p] = 0.0f; }

    const f32x4 zero = {0.0f, 0.0f, 0.0f, 0.0f};
    f32x4 acc[4][4];
#pragma unroll
    for (int mt = 0; mt < 4; ++mt)
#pragma unroll
        for (int nt = 0; nt < 4; ++nt) acc[mt][nt] = zero;

    const float* Ab = X  + (size_t)(bm + r0) * K_DIM + c4 * 4;
    const float* Bb = Pr + (size_t)(bn + r0) * K_DIM + c4 * 4;

    for (int kc = 0; kc < K_DIM / BK; ++kc) {
        const int k0 = kc * BK;

        // global loads issued before barrier #1 so latency overlaps the wait
        float4 av[8], bv[8];
#pragma unroll
        for (int p = 0; p < 8; ++p) {
            av[p] = *(const float4*)(Ab + (size_t)(16 * p) * K_DIM + k0);
            bv[p] = *(const float4*)(Bb + (size_t)(16 * p) * K_DIM + k0);
        }

        __syncthreads();   // previous chunk's ds_reads complete before overwrite

#pragma unroll
        for (int p = 0; p < 8; ++p) {
            asq[p] += av[p].x * av[p].x + av[p].y * av[p].y
                    + av[p].z * av[p].z + av[p].w * av[p].w;
            bsq[p] += bv[p].x * bv[p].x + bv[p].y * bv[p].y
                    + bv[p].z * bv[p].z + bv[p].w * bv[p].w;
            ushort4 ua, ub;
            ua.x = f2bf(av[p].x); ua.y = f2bf(av[p].y);
            ua.z = f2bf(av[p].z); ua.w = f2bf(av[p].w);
            ub.x = f2bf(bv[p].x); ub.y = f2bf(bv[p].y);
            ub.z = f2bf(bv[p].z); ub.w = f2bf(bv[p].w);
            *(ushort4*)&lds_a[(r0 + 16 * p) * BK + c4 * 4] = ua;
            *(ushort4*)&lds_b[(r0 + 16 * p) * BK + c4 * 4] = ub;
            if (write_proto)
                *(float4*)(proto_out + (size_t)(bn + r0 + 16 * p) * K_DIM
                           + k0 + c4 * 4) = bv[p];
        }

        __syncthreads();   // staged tile visible

#pragma unroll
        for (int ks = 0; ks < 2; ++ks) {
            bf16x8 af[4], bfr[4];
#pragma unroll
            for (int mt = 0; mt < 4; ++mt)
                af[mt] = *(const bf16x8*)
                    &lds_a[(wm + mt * 16 + l16) * BK + ks * 32 + quad * 8];
#pragma unroll
            for (int nt = 0; nt < 4; ++nt)
                bfr[nt] = *(const bf16x8*)
                    &lds_b[(wn + nt * 16 + l16) * BK + ks * 32 + quad * 8];
#pragma unroll
            for (int mt = 0; mt < 4; ++mt)
#pragma unroll
                for (int nt = 0; nt < 4; ++nt)
                    acc[mt][nt] = __builtin_amdgcn_mfma_f32_16x16x32_bf16(
                        af[mt], bfr[nt], acc[mt][nt], 0, 0, 0);
        }
    }

    // reduce per-row sums over the 16 staging lanes (xor flips only c4 bits)
#pragma unroll
    for (int p = 0; p < 8; ++p) {
        float a = asq[p], b = bsq[p];
#pragma unroll
        for (int off = 1; off < 16; off <<= 1) {
            a += __shfl_xor(a, off);
            b += __shfl_xor(b, off);
        }
        if (c4 == 0) {
            lds_xsq[r0 + 16 * p] = a;
            lds_psq[r0 + 16 * p] = b;
        }
    }
    __syncthreads();

    // Epilogue: C/D layout col = lane&15, row = quad*4 + i
    float ps[4];
#pragma unroll
    for (int nt = 0; nt < 4; ++nt) ps[nt] = lds_psq[wn + nt * 16 + l16];

#pragma unroll
    for (int mt = 0; mt < 4; ++mt) {
#pragma unroll
        for (int i = 0; i < 4; ++i) {
            const int lr = wm + mt * 16 + quad * 4 + i;   // local row
            const float xs = lds_xsq[lr];
            float* orow = out + (size_t)(bm + lr) * N_PROT + bn + wn + l16;
#pragma unroll
            for (int nt = 0; nt < 4; ++nt)
                orow[nt * 16] = xs + ps[nt] - 2.0f * acc[mt][nt][i];
        }
    }
}

extern "C" void kernel_launch(void* const* d_in, const int* in_sizes, int n_in,
                              void* d_out, int out_size, void* d_ws, size_t ws_size,
                              hipStream_t stream) {
    const float* inputs = (const float*)d_in[0];   // [32,512,768] fp32
    const float* protos = (const float*)d_in[1];   // [512,768]    fp32
    float* out = (float*)d_out;
    float* proto_out = out + (size_t)M_TOK * N_PROT;   // second tuple element

    dim3 grid(N_PROT / 128, M_TOK / 128);   // (4, 128)
    fused_dist_kernel<<<grid, 256, 0, stream>>>(inputs, protos, out, proto_out);
}

// Round 4
// 121.761 us; speedup vs baseline: 1.0895x; 1.0895x over previous
//
#include <hip/hip_runtime.h>
#include <hip/hip_bf16.h>

// Problem: B=32, S=512, P=512, D=768
//   M = B*S = 16384 tokens, N = P = 512 prototypes, K = D = 768
// out[0 .. M*N)            = distances  ||x_m - p_n||^2  (fp32)
// out[M*N .. M*N + N*K)    = prototypes (fp32 passthrough)
//
// Structure (R4): read-A-once.
//   prep_b (tiny): P fp32 -> b_bf (bf16, ws) + p_sq (fp32, ws) + proto passthrough.
//   dist_main: grid 256 blocks (1/CU), 512 thr (8 waves), tile 64 rows x ALL 512 cols.
//     - A stripe read ONCE as fp32 (1 float4/thread/chunk), squared for x_sq,
//       converted in-register to bf16, ds_write to padded LDS (conflict-free).
//     - B chunk (512x32 bf16 = 32 KB) staged via global_load_lds width-16
//       (wave-uniform base + lane*16, no VALU, no ds_write conflicts); B is
//       L2-resident (0.75 MB) so per-block re-reads stay on-die.
//     - 8 waves each compute 64x64 via 4x4 mfma_f32_16x16x32_bf16 over BK=32.
//     - epilogue: out = x_sq + p_sq - 2*acc.

#define M_TOK 16384
#define N_PROT 512
#define K_DIM 768
#define BK 32
#define NCH (K_DIM / BK)   // 24
#define APAD 8             // lds_a row stride = BK+APAD = 40 ushorts = 80 B = 20 banks

typedef __attribute__((ext_vector_type(4))) float f32x4;
typedef __attribute__((ext_vector_type(8))) short bf16x8;

typedef const __attribute__((address_space(1))) unsigned int g_uint;
typedef __attribute__((address_space(3))) unsigned int l_uint;

__device__ inline unsigned short f2bf(float f) {
    // round-to-nearest-even on the bit pattern (finite inputs)
    unsigned int u = __float_as_uint(f);
    u += 0x7fffu + ((u >> 16) & 1u);
    return (unsigned short)(u >> 16);
}

// One wave per prototype row: bf16 convert + ||p||^2 + fp32 passthrough copy.
__global__ __launch_bounds__(256) void prep_b(
    const float* __restrict__ p,
    unsigned short* __restrict__ b_bf, float* __restrict__ p_sq,
    float* __restrict__ proto_out)
{
    const int row  = blockIdx.x * 4 + (threadIdx.x >> 6);
    const int lane = threadIdx.x & 63;

    const float4* src4 = (const float4*)(p + (size_t)row * K_DIM);
    unsigned short* dst = b_bf + (size_t)row * K_DIM;
    float4* pout4 = (float4*)(proto_out + (size_t)row * K_DIM);

    float ssum = 0.0f;
#pragma unroll
    for (int j = 0; j < 3; ++j) {        // 192 float4 per row / 64 lanes
        const int idx = lane + j * 64;
        float4 v = src4[idx];
        ssum += v.x * v.x + v.y * v.y + v.z * v.z + v.w * v.w;
        ushort4 b;
        b.x = f2bf(v.x); b.y = f2bf(v.y); b.z = f2bf(v.z); b.w = f2bf(v.w);
        ((ushort4*)dst)[idx] = b;
        pout4[idx] = v;
    }
#pragma unroll
    for (int off = 32; off > 0; off >>= 1) ssum += __shfl_down(ssum, off);
    if (lane == 0) p_sq[row] = ssum;
}

__global__ __launch_bounds__(512, 2) void dist_main(
    const float* __restrict__ X,             // [M,K] fp32 tokens
    const unsigned short* __restrict__ Bb,   // [N,K] bf16 prototypes
    const float* __restrict__ p_sq,          // [N] fp32
    float* __restrict__ out)                 // [M,N] fp32 distances
{
    __shared__ unsigned short lds_b[N_PROT * BK];        // 32 KB
    __shared__ unsigned short lds_a[64 * (BK + APAD)];   // 5 KB
    __shared__ float lds_xsq[64];

    const int tid  = threadIdx.x;
    const int wave = tid >> 6;           // 0..7
    const int lane = tid & 63;
    const int bm   = blockIdx.x << 6;    // 64-row A stripe
    const int wn   = wave << 6;          // this wave's 64-col slice of N
    const int quad = lane >> 4;          // 0..3
    const int l16  = lane & 15;

    // A staging: thread t -> row t>>3 (0..63), float4 col (t&7)
    const int arow  = tid >> 3;
    const int acol8 = tid & 7;
    const float* aptr = X + (size_t)(bm + arow) * K_DIM + acol8 * 4;

    // B staging: wave stages rows [wave*64, wave*64+64), 4 instrs x 16 rows.
    const int brow = (lane >> 2);          // 0..15 within 16-row group
    const int bcol = (lane & 3) * 8;       // ushort offset (16 B chunks)

    const f32x4 zero = {0.0f, 0.0f, 0.0f, 0.0f};
    f32x4 acc[4][4];
#pragma unroll
    for (int mt = 0; mt < 4; ++mt)
#pragma unroll
        for (int nt = 0; nt < 4; ++nt) acc[mt][nt] = zero;

    float asq = 0.0f;
    f32x4 cur = *(const f32x4*)aptr;   // chunk 0 prefetch

    for (int kc = 0; kc < NCH; ++kc) {
        const int k0 = kc * BK;

        __syncthreads();   // previous chunk's ds_reads complete before overwrite

        // ---- B: global -> LDS, 4 x 1KB per wave, no VGPR round-trip
#pragma unroll
        for (int j = 0; j < 4; ++j) {
            const unsigned short* gb = Bb
                + (size_t)(wn + j * 16 + brow) * K_DIM + k0 + bcol;
            __builtin_amdgcn_global_load_lds((g_uint*)gb,
                (l_uint*)&lds_b[(wn + j * 16) * BK], 16, 0, 0);
        }

        // ---- A: prefetch next chunk, then square+convert+stage current
        f32x4 nxt = cur;
        if (kc + 1 < NCH)
            nxt = *(const f32x4*)(aptr + k0 + BK);
        asq += cur.x * cur.x + cur.y * cur.y + cur.z * cur.z + cur.w * cur.w;
        ushort4 ua;
        ua.x = f2bf(cur.x); ua.y = f2bf(cur.y);
        ua.z = f2bf(cur.z); ua.w = f2bf(cur.w);
        *(ushort4*)&lds_a[arow * (BK + APAD) + acol8 * 4] = ua;
        cur = nxt;

        __syncthreads();   // staged tile visible (drains global_load_lds)

        bf16x8 af[4], bfr[4];
#pragma unroll
        for (int mt = 0; mt < 4; ++mt)
            af[mt] = *(const bf16x8*)
                &lds_a[(mt * 16 + l16) * (BK + APAD) + quad * 8];
#pragma unroll
        for (int nt = 0; nt < 4; ++nt)
            bfr[nt] = *(const bf16x8*)
                &lds_b[(wn + nt * 16 + l16) * BK + quad * 8];

#pragma unroll
        for (int mt = 0; mt < 4; ++mt)
#pragma unroll
            for (int nt = 0; nt < 4; ++nt)
                acc[mt][nt] = __builtin_amdgcn_mfma_f32_16x16x32_bf16(
                    af[mt], bfr[nt], acc[mt][nt], 0, 0, 0);
    }

    // ---- x_sq: reduce over the 8 staging lanes of each row (xor in low 3 bits)
#pragma unroll
    for (int off = 1; off < 8; off <<= 1) asq += __shfl_xor(asq, off);
    if (acol8 == 0) lds_xsq[arow] = asq;
    __syncthreads();

    // ---- epilogue: C/D layout col = lane&15, row = quad*4 + i
    float ps[4];
#pragma unroll
    for (int nt = 0; nt < 4; ++nt) ps[nt] = p_sq[wn + nt * 16 + l16];

#pragma unroll
    for (int mt = 0; mt < 4; ++mt) {
#pragma unroll
        for (int i = 0; i < 4; ++i) {
            const int lr = mt * 16 + quad * 4 + i;   // local row 0..63
            const float xs = lds_xsq[lr];
            float* orow = out + (size_t)(bm + lr) * N_PROT + wn + l16;
#pragma unroll
            for (int nt = 0; nt < 4; ++nt)
                orow[nt * 16] = xs + ps[nt] - 2.0f * acc[mt][nt][i];
        }
    }
}

extern "C" void kernel_launch(void* const* d_in, const int* in_sizes, int n_in,
                              void* d_out, int out_size, void* d_ws, size_t ws_size,
                              hipStream_t stream) {
    const float* inputs = (const float*)d_in[0];   // [32,512,768] fp32
    const float* protos = (const float*)d_in[1];   // [512,768]    fp32
    float* out = (float*)d_out;
    float* proto_out = out + (size_t)M_TOK * N_PROT;   // second tuple element

    // ws layout: b_bf 512*768*2 = 786,432 B ; p_sq 512*4 = 2,048 B
    char* ws = (char*)d_ws;
    unsigned short* b_bf = (unsigned short*)ws;
    float* p_sq = (float*)(ws + 786432);

    prep_b<<<128, 256, 0, stream>>>(protos, b_bf, p_sq, proto_out);
    dist_main<<<M_TOK / 64, 512, 0, stream>>>(inputs, b_bf, p_sq, out);
}

// Round 5
// 116.072 us; speedup vs baseline: 1.1429x; 1.0490x over previous
//
#include <hip/hip_runtime.h>
#include <hip/hip_bf16.h>

// Problem: B=32, S=512, P=512, D=768
//   M = B*S = 16384 tokens, N = P = 512 prototypes, K = D = 768
// out[0 .. M*N)            = distances  ||x_m - p_n||^2  (fp32)
// out[M*N .. M*N + N*K)    = prototypes (fp32 passthrough)
//
// R5 structure: BARRIER-FREE K-loop.
//   prep_b: prototypes fp32 -> b_bf (bf16 ws) + p_sq + fp32 passthrough.
//   dist_main: grid 256 (1 block/CU), 512 thr (8 waves).
//     - A stripe (64 rows x 768) staged ONCE: fp32 global -> x_sq (exact fp32)
//       -> bf16 -> padded LDS (stride 776 => 2-way bank aliasing only = free).
//       ONE __syncthreads; the K-loop has ZERO barriers.
//     - Each wave owns a 64-col slice of N: B fragments loaded directly
//       global->VGPR (contiguous 16B dwordx4 per lane, already bf16, L2-hot),
//       software-pipelined one chunk ahead => compiler emits partial vmcnt
//       waits (never a full drain) -- the AITER pattern, no barrier needed.
//     - 4x4 grid of mfma_f32_16x16x32_bf16 per wave, 24 K-chunks.
//     - epilogue: out = x_sq + p_sq - 2*acc.

#define M_TOK 16384
#define N_PROT 512
#define K_DIM 768
#define BK 32
#define NCH (K_DIM / BK)     // 24
#define ASTR (K_DIM + 8)     // 776: padded LDS row stride in bf16 units

typedef __attribute__((ext_vector_type(4))) float f32x4;
typedef __attribute__((ext_vector_type(8))) short bf16x8;

__device__ inline unsigned short f2bf(float f) {
    // round-to-nearest-even on the bit pattern (finite inputs)
    unsigned int u = __float_as_uint(f);
    u += 0x7fffu + ((u >> 16) & 1u);
    return (unsigned short)(u >> 16);
}

// One wave per prototype row: bf16 convert + ||p||^2 + fp32 passthrough copy.
__global__ __launch_bounds__(256) void prep_b(
    const float* __restrict__ p,
    unsigned short* __restrict__ b_bf, float* __restrict__ p_sq,
    float* __restrict__ proto_out)
{
    const int row  = blockIdx.x * 4 + (threadIdx.x >> 6);
    const int lane = threadIdx.x & 63;

    const float4* src4 = (const float4*)(p + (size_t)row * K_DIM);
    unsigned short* dst = b_bf + (size_t)row * K_DIM;
    float4* pout4 = (float4*)(proto_out + (size_t)row * K_DIM);

    float ssum = 0.0f;
#pragma unroll
    for (int j = 0; j < 3; ++j) {        // 192 float4 per row / 64 lanes
        const int idx = lane + j * 64;
        float4 v = src4[idx];
        ssum += v.x * v.x + v.y * v.y + v.z * v.z + v.w * v.w;
        ushort4 b;
        b.x = f2bf(v.x); b.y = f2bf(v.y); b.z = f2bf(v.z); b.w = f2bf(v.w);
        ((ushort4*)dst)[idx] = b;
        pout4[idx] = v;
    }
#pragma unroll
    for (int off = 32; off > 0; off >>= 1) ssum += __shfl_down(ssum, off);
    if (lane == 0) p_sq[row] = ssum;
}

__global__ __launch_bounds__(512, 2) void dist_main(
    const float* __restrict__ X,             // [M,K] fp32 tokens
    const unsigned short* __restrict__ Bb,   // [N,K] bf16 prototypes (ws)
    const float* __restrict__ p_sq,          // [N] fp32
    float* __restrict__ out)                 // [M,N] fp32 distances
{
    __shared__ unsigned short lds_a[64 * ASTR];   // ~97 KB, full-K A stripe
    __shared__ float lds_xsq[64];

    const int tid  = threadIdx.x;
    const int wave = tid >> 6;           // 0..7
    const int lane = tid & 63;
    const int bm   = blockIdx.x << 6;    // 64-row A stripe
    const int wn   = wave << 6;          // this wave's 64-col slice of N
    const int quad = lane >> 4;          // 0..3
    const int l16  = lane & 15;

    // ---- one-time A staging: fp32 -> (x_sq, bf16 LDS) ----
    const int ar = tid >> 3;             // 0..63 row
    const int ac = tid & 7;              // float4 col base
    const float* aptr = X + (size_t)(bm + ar) * K_DIM;
    float asq = 0.0f;
#pragma unroll
    for (int j = 0; j < 24; ++j) {
        const int c4 = ac + 8 * j;       // float4 index 0..191
        float4 v = *(const float4*)(aptr + (size_t)c4 * 4);
        asq += v.x * v.x + v.y * v.y + v.z * v.z + v.w * v.w;
        ushort4 u;
        u.x = f2bf(v.x); u.y = f2bf(v.y); u.z = f2bf(v.z); u.w = f2bf(v.w);
        *(ushort4*)&lds_a[ar * ASTR + c4 * 4] = u;
    }
#pragma unroll
    for (int off = 1; off < 8; off <<= 1) asq += __shfl_xor(asq, off);
    if (ac == 0) lds_xsq[ar] = asq;

    __syncthreads();   // the ONLY barrier

    // ---- barrier-free K-loop ----
    const f32x4 zero = {0.0f, 0.0f, 0.0f, 0.0f};
    f32x4 acc[4][4];
#pragma unroll
    for (int mt = 0; mt < 4; ++mt)
#pragma unroll
        for (int nt = 0; nt < 4; ++nt) acc[mt][nt] = zero;

    // per-lane B fragment pointers: row (wn + nt*16 + l16), 16B chunk at quad*8
    const unsigned short* bp = Bb + (size_t)(wn + l16) * K_DIM + quad * 8;

    bf16x8 bcur[4], bnxt[4];
#pragma unroll
    for (int nt = 0; nt < 4; ++nt)
        bcur[nt] = *(const bf16x8*)(bp + (size_t)(nt * 16) * K_DIM);

    for (int kc = 0; kc < NCH; ++kc) {
        const int k0 = kc * BK;
        if (kc + 1 < NCH) {
#pragma unroll
            for (int nt = 0; nt < 4; ++nt)
                bnxt[nt] = *(const bf16x8*)(bp + (size_t)(nt * 16) * K_DIM + k0 + BK);
        }

        bf16x8 af[4];
#pragma unroll
        for (int mt = 0; mt < 4; ++mt)
            af[mt] = *(const bf16x8*)&lds_a[(mt * 16 + l16) * ASTR + k0 + quad * 8];

#pragma unroll
        for (int mt = 0; mt < 4; ++mt)
#pragma unroll
            for (int nt = 0; nt < 4; ++nt)
                acc[mt][nt] = __builtin_amdgcn_mfma_f32_16x16x32_bf16(
                    af[mt], bcur[nt], acc[mt][nt], 0, 0, 0);

#pragma unroll
        for (int nt = 0; nt < 4; ++nt) bcur[nt] = bnxt[nt];
    }

    // ---- epilogue: C/D layout col = lane&15, row = quad*4 + i ----
    float ps[4];
#pragma unroll
    for (int nt = 0; nt < 4; ++nt) ps[nt] = p_sq[wn + nt * 16 + l16];

#pragma unroll
    for (int mt = 0; mt < 4; ++mt) {
#pragma unroll
        for (int i = 0; i < 4; ++i) {
            const int lr = mt * 16 + quad * 4 + i;   // local row 0..63
            const float xs = lds_xsq[lr];
            float* orow = out + (size_t)(bm + lr) * N_PROT + wn + l16;
#pragma unroll
            for (int nt = 0; nt < 4; ++nt)
                orow[nt * 16] = xs + ps[nt] - 2.0f * acc[mt][nt][i];
        }
    }
}

extern "C" void kernel_launch(void* const* d_in, const int* in_sizes, int n_in,
                              void* d_out, int out_size, void* d_ws, size_t ws_size,
                              hipStream_t stream) {
    const float* inputs = (const float*)d_in[0];   // [32,512,768] fp32
    const float* protos = (const float*)d_in[1];   // [512,768]    fp32
    float* out = (float*)d_out;
    float* proto_out = out + (size_t)M_TOK * N_PROT;   // second tuple element

    // ws layout: b_bf 512*768*2 = 786,432 B ; p_sq 512*4 = 2,048 B
    char* ws = (char*)d_ws;
    unsigned short* b_bf = (unsigned short*)ws;
    float* p_sq = (float*)(ws + 786432);

    prep_b<<<128, 256, 0, stream>>>(protos, b_bf, p_sq, proto_out);
    dist_main<<<M_TOK / 64, 512, 0, stream>>>(inputs, b_bf, p_sq, out);
}